// Round 7
// baseline (654.613 us; speedup 1.0000x reference)
//
#include <hip/hip_runtime.h>
#include <hip/hip_bf16.h>
#include <cstdint>
#include <cstddef>

// Problem constants (AttentionLayerEnhance: B=4, L=S=2048, D=512, H=8, window=32)
// I/O: all inputs f32, both outputs f32. Internal: bf16 MFMA, f32 accum.
// Timing note (R3-R5 accounting): ~470us of dur_us is harness poison/restore
// (2.215GB fills @ ~350us visible in profile); our kernels are ~185us.
#define D_MODEL 512
#define N_HEADS 8
#define HDIM 64
#define SEQ 2048
#define B_SZ 4
#define M_TOT (B_SZ * SEQ)                 // 8192 rows for all projections
#define ATTN_ROWS (B_SZ * N_HEADS * SEQ)   // 65536 rows of the attn matrix
#define PROJ_ELEMS ((size_t)M_TOT * D_MODEL)   // 4,194,304

typedef __bf16 bf16x8 __attribute__((ext_vector_type(8)));
typedef float  f32x4  __attribute__((ext_vector_type(4)));

__device__ __forceinline__ unsigned short f2bf(float x) {
    __bf16 b = (__bf16)x;
    return __builtin_bit_cast(unsigned short, b);
}
__device__ __forceinline__ float bf2f(unsigned short u) {
    __bf16 b = __builtin_bit_cast(__bf16, u);
    return (float)b;
}

// ---------------------------------------------------------------------------
// 512x512 transpose (f32 W[k][n] -> bf16 Wt[n][k]). z selects weight.
// ---------------------------------------------------------------------------
struct TransArgs {
    const float* W[4];
    unsigned short* Wt[4];
};

__global__ void transpose_k(TransArgs ta) {
    __shared__ float tile[32][33];
    const int z = blockIdx.z;
    const float* W = ta.W[z];
    unsigned short* Wt = ta.Wt[z];
    int x = blockIdx.x * 32 + threadIdx.x;
    int y0 = blockIdx.y * 32;
    for (int j = threadIdx.y; j < 32; j += 8)
        tile[j][threadIdx.x] = W[(size_t)(y0 + j) * D_MODEL + x];
    __syncthreads();
    int xo = blockIdx.y * 32 + threadIdx.x;
    int yo0 = blockIdx.x * 32;
    for (int j = threadIdx.y; j < 32; j += 8)
        Wt[(size_t)(yo0 + j) * D_MODEL + xo] = f2bf(tile[threadIdx.x][j]);
}

// ---------------------------------------------------------------------------
// bf16 GEMM: C[M,512] = A[M,512] * W + bias. A source F32 (converted to bf16
// in-register during LDS staging). Wt[N,K] bf16. 128x128 tile, BK=64,
// 4 waves (2x2 of 64x64), mfma_f32_16x16x32_bf16, 4x4 acc/wave.
// 1-D grid with XCD-aware decode: f = z*256 + xc*32 + y*8 + xl;
// x = xc*8+xl (m-tile), y (n-tile). The 4 y-tiles sharing an A-block have
// dispatch ids differing by 8 => same XCD (round-robin) => A fetched once
// per XCD L2 instead of up to 4x from HBM.
// ---------------------------------------------------------------------------
struct GemmArgs {
    const float* A[3];
    const unsigned short* Wt[3];
    const float* bias[3];
    void* C[3];
};

#define LDSTRIDE 72

template <int F32OUT>
__global__ __launch_bounds__(256, 2) void gemm_bt(GemmArgs ga) {
    __shared__ __align__(16) unsigned short lsA[128 * LDSTRIDE];
    __shared__ __align__(16) unsigned short lsB[128 * LDSTRIDE];

    const int f = blockIdx.x;
    const int z = f >> 8;
    const int xt = ((f >> 5) & 7) * 8 + (f & 7);   // m-tile 0..63
    const int yt = (f >> 3) & 3;                   // n-tile 0..3
    const float* __restrict__ A           = ga.A[z];
    const unsigned short* __restrict__ Wt = ga.Wt[z];
    const float* __restrict__ bias        = ga.bias[z];

    const int m0 = xt * 128;
    const int n0 = yt * 128;
    const int tid = threadIdx.x;
    const int lane = tid & 63;
    const int wid = tid >> 6;
    const int wm = (wid >> 1) * 64;
    const int wn = (wid & 1) * 64;
    const int lrow = lane & 15;
    const int quad = lane >> 4;

    f32x4 acc[4][4];
#pragma unroll
    for (int i = 0; i < 4; ++i)
#pragma unroll
        for (int j = 0; j < 4; ++j)
            acc[i][j] = (f32x4){0.f, 0.f, 0.f, 0.f};

    for (int kt = 0; kt < D_MODEL; kt += 64) {
        __syncthreads();
#pragma unroll
        for (int p = 0; p < 4; ++p) {
            int c = p * 256 + tid;
            int r = c >> 3;
            int col = (c & 7) << 3;
            const float* src = &A[(size_t)(m0 + r) * D_MODEL + kt + col];
            float4 a0 = *(const float4*)src;
            float4 a1 = *(const float4*)(src + 4);
            unsigned short t8[8];
            t8[0] = f2bf(a0.x); t8[1] = f2bf(a0.y); t8[2] = f2bf(a0.z); t8[3] = f2bf(a0.w);
            t8[4] = f2bf(a1.x); t8[5] = f2bf(a1.y); t8[6] = f2bf(a1.z); t8[7] = f2bf(a1.w);
            *(uint4*)&lsA[r * LDSTRIDE + col] = *(const uint4*)t8;
        }
#pragma unroll
        for (int p = 0; p < 4; ++p) {
            int c = p * 256 + tid;
            int r = c >> 3;
            int col = (c & 7) << 3;
            *(uint4*)&lsB[r * LDSTRIDE + col] =
                *(const uint4*)&Wt[(size_t)(n0 + r) * D_MODEL + kt + col];
        }
        __syncthreads();
#pragma unroll
        for (int ks = 0; ks < 2; ++ks) {
            const int ko = ks * 32 + quad * 8;
            bf16x8 af[4], bfr[4];
#pragma unroll
            for (int mt = 0; mt < 4; ++mt)
                af[mt] = *(const bf16x8*)&lsA[(wm + mt * 16 + lrow) * LDSTRIDE + ko];
#pragma unroll
            for (int nt = 0; nt < 4; ++nt)
                bfr[nt] = *(const bf16x8*)&lsB[(wn + nt * 16 + lrow) * LDSTRIDE + ko];
#pragma unroll
            for (int mt = 0; mt < 4; ++mt)
#pragma unroll
                for (int nt = 0; nt < 4; ++nt)
                    acc[mt][nt] = __builtin_amdgcn_mfma_f32_16x16x32_bf16(
                        af[mt], bfr[nt], acc[mt][nt], 0, 0, 0);
        }
    }

    // Epilogue: C/D layout col=lane&15, row=quad*4+reg (m89-verified).
#pragma unroll
    for (int nt = 0; nt < 4; ++nt) {
        const int gcol = n0 + wn + nt * 16 + lrow;
        const float bv = bias[gcol];
#pragma unroll
        for (int mt = 0; mt < 4; ++mt) {
            const int grow = m0 + wm + mt * 16 + quad * 4;
#pragma unroll
            for (int r = 0; r < 4; ++r) {
                const float v = acc[mt][nt][r] + bv;
                if (F32OUT) {
                    // d_out: never re-read -> nontemporal
                    __builtin_nontemporal_store(
                        v, &((float*)ga.C[z])[(size_t)(grow + r) * D_MODEL + gcol]);
                } else {
                    ((unsigned short*)ga.C[z])[(size_t)(grow + r) * D_MODEL + gcol] = f2bf(v);
                }
            }
        }
    }
}

// ---------------------------------------------------------------------------
// Tiled band attention + full attn-row writer. One block per (b, h, 64-row
// t-tile). K/V rows [t0-16, t0+63] staged in LDS. Lane = (r = row 0..15,
// c = d-quarter 0..3). Scores: 16 reg-FMAs per key + 2 quad shuffles.
// Softmax per-lane. Band probs -> LDS; block streams the 64 full 2048-col
// f32 rows (zeros + band) with nontemporal f32x4 stores (clang ext-vector —
// __builtin_nontemporal_store rejects HIP_vector_type float4).
// ---------------------------------------------------------------------------
#define KV_ROWS 80
#define LROW 72

__device__ __forceinline__ void load16f(const unsigned short* p, float* out) {
    bf16x8 a = *(const bf16x8*)p;
    bf16x8 b = *(const bf16x8*)(p + 8);
#pragma unroll
    for (int i = 0; i < 8; ++i) { out[i] = (float)a[i]; out[8 + i] = (float)b[i]; }
}

__global__ __launch_bounds__(256, 4) void attn2_k(
    const unsigned short* __restrict__ Q,
    const unsigned short* __restrict__ K,
    const unsigned short* __restrict__ V,
    const float* __restrict__ gamma_p,
    float* __restrict__ attn_out,
    float* __restrict__ ctx) {
    __shared__ __align__(16) unsigned short lk[KV_ROWS * LROW];
    __shared__ __align__(16) unsigned short lv[KV_ROWS * LROW];
    __shared__ float pband[64][20];            // [row-in-tile][j], padded

    const int bh = blockIdx.y;                 // b*8 + h
    const int t0 = blockIdx.x * 64;
    const int b = bh >> 3;
    const int h = bh & 7;
    const int tid = threadIdx.x;
    const int w = tid >> 6;
    const int lane = tid & 63;
    const int r = lane >> 2;
    const int c = lane & 3;

    const float g = gamma_p[0];
    const float rs = 0.044194173824159216f;    // 1/sqrt(512)

    // Stage K/V rows [t0-16, t0+63] (zeros for negative rows).
    const size_t srcbase = (size_t)b * SEQ * D_MODEL + (size_t)h * HDIM;
    for (int idx = tid; idx < KV_ROWS * 8; idx += 256) {
        const int row = idx >> 3;
        const int ch = (idx & 7) * 8;
        const int grow = t0 - 16 + row;
        uint4 kv4 = {0, 0, 0, 0};
        uint4 vv4 = {0, 0, 0, 0};
        if (grow >= 0) {
            const size_t off = srcbase + (size_t)grow * D_MODEL + ch;
            kv4 = *(const uint4*)&K[off];
            vv4 = *(const uint4*)&V[off];
        }
        *(uint4*)&lk[row * LROW + ch] = kv4;
        *(uint4*)&lv[row * LROW + ch] = vv4;
    }
    __syncthreads();

    // Per-lane Q segment: row gr, d-cols c*16..c*16+15 (within this head).
    const int gr = t0 + w * 16 + r;            // global t
    const size_t qoff = srcbase + (size_t)gr * D_MODEL + c * 16;
    float qv[16];
    load16f(&Q[qoff], qv);

    // Scores over the 17-key band (j: s = gr-16+j).
    const int lr0 = w * 16 + r;                // LDS row for j=0
    float scr[17];
#pragma unroll
    for (int j = 0; j < 17; ++j) {
        float kvv[16];
        load16f(&lk[(lr0 + j) * LROW + c * 16], kvv);
        float part = 0.f;
#pragma unroll
        for (int i = 0; i < 16; ++i) part = fmaf(qv[i], kvv[i], part);
        part += __shfl_xor(part, 1, 64);
        part += __shfl_xor(part, 2, 64);       // all 4 quad lanes now have full dot
        const float dec = __expf(-g * (float)(16 - j));
        scr[j] = part * rs * dec;
        if (gr - 16 + j < 0) scr[j] = -__builtin_inff();
    }

    // Per-lane softmax (j=16 always valid => m finite).
    float m = scr[0];
#pragma unroll
    for (int j = 1; j < 17; ++j) m = fmaxf(m, scr[j]);
    float l = 0.f;
#pragma unroll
    for (int j = 0; j < 17; ++j) { scr[j] = __expf(scr[j] - m); l += scr[j]; }
    const float inv = 1.f / l;

    // PV: out[gr][c*16+i] = sum_j p[j] * V[s][c*16+i].
    float acc[16];
#pragma unroll
    for (int i = 0; i < 16; ++i) acc[i] = 0.f;
#pragma unroll
    for (int j = 0; j < 17; ++j) {
        float vv[16];
        load16f(&lv[(lr0 + j) * LROW + c * 16], vv);
#pragma unroll
        for (int i = 0; i < 16; ++i) acc[i] = fmaf(scr[j], vv[i], acc[i]);
    }

    // ctx store (f32, re-read by out-proj -> normal cached stores).
    float* cp = &ctx[qoff];
#pragma unroll
    for (int i = 0; i < 16; i += 4) {
        f32x4 v = {acc[i] * inv, acc[i + 1] * inv, acc[i + 2] * inv, acc[i + 3] * inv};
        *(f32x4*)&cp[i] = v;
    }

    // Publish band probabilities, then stream full rows (zeros + band).
    for (int j = c; j < 17; j += 4) pband[lr0][j] = scr[j] * inv;
    __syncthreads();

    const size_t rowbase = ((size_t)bh * SEQ + t0) * SEQ;
    for (int i = tid; i < 64 * 512; i += 256) {
        const int row = i >> 9;                 // 0..63
        const int c4 = i & 511;                 // f32x4 index in row
        const int t = t0 + row;
        const int s_lo = (t - 16 < 0) ? 0 : t - 16;
        const int lo4 = s_lo >> 2;
        const int hi4 = t >> 2;
        f32x4 v = {0.f, 0.f, 0.f, 0.f};
        if ((unsigned)(c4 - lo4) <= (unsigned)(hi4 - lo4)) {
            const int col0 = c4 * 4;
#pragma unroll
            for (int k = 0; k < 4; ++k) {
                const int col = col0 + k;
                v[k] = (col >= s_lo && col <= t) ? pband[row][col - (t - 16)] : 0.f;
            }
        }
        __builtin_nontemporal_store(
            v, (f32x4*)&attn_out[rowbase + (size_t)row * SEQ + (c4 << 2)]);
    }
}

// ---------------------------------------------------------------------------
// ws layout: [Qp|Kp|Vp: bf16 3x8MB][WT: bf16 4x512KB][Ctx: f32 16MB] ~= 42 MB
// ---------------------------------------------------------------------------
extern "C" void kernel_launch(void* const* d_in, const int* in_sizes, int n_in,
                              void* d_out, int out_size, void* d_ws, size_t ws_size,
                              hipStream_t stream) {
    const float* queries = (const float*)d_in[0];
    const float* keys    = (const float*)d_in[1];
    const float* values  = (const float*)d_in[2];
    // d_in[3] attn_mask: fixed causal triu — folded analytically.
    const float* Wq = (const float*)d_in[4];
    const float* bq = (const float*)d_in[5];
    const float* Wk = (const float*)d_in[6];
    const float* bk = (const float*)d_in[7];
    const float* Wv = (const float*)d_in[8];
    const float* bv = (const float*)d_in[9];
    const float* Wo = (const float*)d_in[10];
    const float* bo = (const float*)d_in[11];
    const float* gamma = (const float*)d_in[12];

    char* ws = (char*)d_ws;
    unsigned short* Qp  = (unsigned short*)ws;
    unsigned short* Kp  = Qp + PROJ_ELEMS;
    unsigned short* Vp  = Kp + PROJ_ELEMS;
    unsigned short* WT  = Vp + PROJ_ELEMS;
    unsigned short* WqT = WT;
    unsigned short* WkT = WT + 262144;
    unsigned short* WvT = WT + 2 * 262144;
    unsigned short* WoT = WT + 3 * 262144;
    float* Ctx = (float*)(WT + 4 * 262144);

    float* out_p  = (float*)d_out;            // [8192,512] f32
    float* attn_p = out_p + PROJ_ELEMS;       // [65536,2048] f32

    // 1) weight transposes (f32 in, bf16 out)
    TransArgs ta;
    ta.W[0] = Wq;  ta.W[1] = Wk;  ta.W[2] = Wv;  ta.W[3] = Wo;
    ta.Wt[0] = WqT; ta.Wt[1] = WkT; ta.Wt[2] = WvT; ta.Wt[3] = WoT;
    transpose_k<<<dim3(16, 16, 4), dim3(32, 8), 0, stream>>>(ta);

    // 2) fused QKV projections (1-D XCD-swizzled grid: 3*256 blocks)
    GemmArgs gq;
    gq.A[0] = queries; gq.A[1] = keys;  gq.A[2] = values;
    gq.Wt[0] = WqT;    gq.Wt[1] = WkT;  gq.Wt[2] = WvT;
    gq.bias[0] = bq;   gq.bias[1] = bk; gq.bias[2] = bv;
    gq.C[0] = Qp;      gq.C[1] = Kp;    gq.C[2] = Vp;
    gemm_bt<0><<<768, 256, 0, stream>>>(gq);

    // 3) tiled band attention: full f32 attn rows (band + zeros) + f32 ctx
    attn2_k<<<dim3(SEQ / 64, B_SZ * N_HEADS), 256, 0, stream>>>(
        Qp, Kp, Vp, gamma, attn_p, Ctx);

    // 4) output projection -> f32 out region of d_out (256 blocks)
    GemmArgs go;
    go.A[0] = Ctx;   go.Wt[0] = WoT; go.bias[0] = bo; go.C[0] = out_p;
    go.A[1] = Ctx;   go.Wt[1] = WoT; go.bias[1] = bo; go.C[1] = out_p;
    go.A[2] = Ctx;   go.Wt[2] = WoT; go.bias[2] = bo; go.C[2] = out_p;
    gemm_bt<1><<<256, 256, 0, stream>>>(go);
}